// Round 5
// baseline (288.837 us; speedup 1.0000x reference)
//
#include <hip/hip_runtime.h>
#include <cstdint>
#include <cstddef>

#define CIN   128
#define COUT  256
#define HW    64
#define NSP   4096      // 64*64 spatial
#define KTOT  1152      // CIN*9
#define BATCH 32
#define PDROP 0.2f
#define LDT   40        // fallback conv LDS stride (bf16 elems)
#define WLD   1160      // prepass weight tile stride (elems)

__device__ __forceinline__ unsigned short f2bf(float f) {
    unsigned int u = __builtin_bit_cast(unsigned int, f);
    u += 0x7fffu + ((u >> 16) & 1u);   // round-to-nearest-even
    return (unsigned short)(u >> 16);
}

// 128 B of guaranteed zeros for OOB halo DMA source (never written)
__device__ __align__(16) unsigned short g_zeros[64] = {0};

// async global->LDS, 16 B per lane; LDS dest = wave-uniform base + lane*16
__device__ __forceinline__ void gl_lds16(const unsigned short* g, unsigned short* l) {
    __builtin_amdgcn_global_load_lds(
        (const __attribute__((address_space(1))) unsigned int*)g,
        (__attribute__((address_space(3))) unsigned int*)l,
        16, 0, 0);
}

// ---------------------------------------------------------------------------
// wt2 layout for 32x32x16 MFMA, 1-KB chunk units (64 lanes x 16 B):
//   chunk = (((slab*9 + tap)*4 + ks)*2 + wm2)*2 + mi        (288 per (b,mb))
//   lane l within chunk: row  = mb*128 + wm2*64 + mi*32 + (l&31)
//                        ch8  = slab*64 + ks*16 + (l>>5)*8  (8 bf16, tap r)
// Conv A-load for wave(wm2), phase(slab,tap,ks), frag mi is exactly
//   base + lane*16 -> ideal coalesced 1 KiB/instruction.
// ---------------------------------------------------------------------------
// Fused pre-pass (single launch):
//  blocks [0,512):    weight -> wt2. Block owns (b,mb,wm2,mi,h) = 16 rows
//                     (h = which 16-row half of the mi 32-row group).
//                     Coalesced flat float4 reads, LDS tap-major transpose,
//                     256-B coalesced chunk-piece writes.
//  blocks [512,2560): x NCHW fp32 -> xt[b][hw][ch] bf16 (NHWC), via u32
//                     channel-pair tile stride 65 (2-way free both phases).
__global__ __launch_bounds__(256) void prepass(
        const float* __restrict__ weight, const float* __restrict__ u_w,
        const float* __restrict__ x,
        unsigned short* __restrict__ wt2, unsigned short* __restrict__ xt)
{
    __shared__ __align__(16) unsigned char smem[16 * WLD * 2];   // 37120 B
    const int t256 = threadIdx.x;

    if (blockIdx.x < 512) {
        unsigned short* tile16 = reinterpret_cast<unsigned short*>(smem);
        const int wb  = blockIdx.x;
        const int b   = wb >> 4;
        const int mb  = (wb >> 3) & 1;
        const int wm2 = (wb >> 2) & 1;
        const int mi  = (wb >> 1) & 1;
        const int h   = wb & 1;
        const int obase = mb * 128 + wm2 * 64 + mi * 32 + h * 16;

        // ---- coalesced load + mask + LDS transpose to tile16[row][r*128+i]
        const float* wsrc = weight + (size_t)obase * KTOT;
        const float* usrc = u_w + (size_t)(b * COUT + obase) * KTOT;
        #pragma unroll
        for (int j = 0; j < 18; ++j) {
            const int f4 = j * 256 + t256;          // 0..4607 float4s, contiguous
            const float4 wv = reinterpret_cast<const float4*>(wsrc)[f4];
            const float4 uv = reinterpret_cast<const float4*>(usrc)[f4];
            const float w4[4] = {wv.x, wv.y, wv.z, wv.w};
            const float u4[4] = {uv.x, uv.y, uv.z, uv.w};
            #pragma unroll
            for (int e = 0; e < 4; ++e) {
                const int fl  = f4 * 4 + e;         // flat elem in 16x1152
                const int row = fl / KTOT;          // const-div -> mul/shift
                const int ks  = fl - row * KTOT;    // i*9 + r
                const int i   = ks / 9;
                const int r   = ks - 9 * i;
                tile16[row * WLD + r * CIN + i] =
                    f2bf((u4[e] > PDROP) ? w4[e] : 0.f);
            }
        }
        __syncthreads();

        // ---- write phase: block writes 72 chunks x 2 half-rows (32 lanes
        // per chunk belong to this block's 16 rows). 256-B coalesced pieces.
        const size_t blkbase = ((size_t)(b * 2 + mb)) * 18432;   // 16B units
        #pragma unroll
        for (int j = 0; j < 9; ++j) {
            const int g    = j * 256 + t256;       // 0..2303
            const int c    = g >> 5;               // chunk-in-block 0..71
            const int slot = g & 31;
            const int lsub = slot & 15;            // row within this 16-row half
            const int lhi2 = slot >> 4;            // ch8 high bit
            const int lane = lhi2 * 32 + h * 16 + lsub;
            const int slab = c / 36;
            const int rem  = c - slab * 36;
            const int tap  = rem >> 2;
            const int ks   = rem & 3;
            const uint4 v = *reinterpret_cast<const uint4*>(
                &tile16[lsub * WLD + tap * CIN + slab * 64 + ks * 16 + lhi2 * 8]);
            const int chunk = (((slab * 9 + tap) * 4 + ks) * 2 + wm2) * 2 + mi;
            const size_t dst16 = blkbase + (size_t)chunk * 64 + lane;
            *reinterpret_cast<uint4*>(wt2 + dst16 * 8) = v;
        }
    } else {
        unsigned int* shp = reinterpret_cast<unsigned int*>(smem);
        const int bidx = blockIdx.x - 512;
        const int b    = bidx >> 6;
        const int hw0  = (bidx & 63) * 64;
        const int ib   = t256 >> 4;                // 0..15
        const int hw4  = (t256 & 15) * 4;          // local hw row group
        #pragma unroll
        for (int j = 0; j < 4; ++j) {
            const int p = ib + 16 * j;             // channel-pair 0..63
            const float4 v0 = *reinterpret_cast<const float4*>(
                x + ((size_t)(b * CIN + 2 * p)) * NSP + hw0 + hw4);
            const float4 v1 = *reinterpret_cast<const float4*>(
                x + ((size_t)(b * CIN + 2 * p + 1)) * NSP + hw0 + hw4);
            const float e0[4] = {v0.x, v0.y, v0.z, v0.w};
            const float e1[4] = {v1.x, v1.y, v1.z, v1.w};
            #pragma unroll
            for (int c = 0; c < 4; ++c) {
                const unsigned int val =
                    (unsigned int)f2bf(e0[c]) | ((unsigned int)f2bf(e1[c]) << 16);
                shp[(hw4 + c) * 65 + p] = val;     // bank=(hw+p)%32: 2-way free
            }
        }
        __syncthreads();
        #pragma unroll
        for (int j = 0; j < 4; ++j) {
            const int idx  = j * 256 + t256;       // 0..1023
            const int row  = idx >> 4;             // hw_loc 0..63
            const int part = idx & 15;             // 16 B chunk (4 u32 pairs)
            uint4 v;
            v.x = shp[row * 65 + part * 4 + 0];
            v.y = shp[row * 65 + part * 4 + 1];
            v.z = shp[row * 65 + part * 4 + 2];
            v.w = shp[row * 65 + part * 4 + 3];
            *reinterpret_cast<uint4*>(
                xt + ((size_t)(b * NSP + hw0 + row)) * CIN + part * 8) = v;
        }
    }
}

// ---------------------------------------------------------------------------
// Main conv v9: v7 skeleton (LDS-resident X-tile, direct-to-reg coalesced A,
// 3 barriers/block, XCD-clustered swizzle) but with 32x32x16 bf16 MFMA:
// same FLOPs in 17% fewer MFMA-pipe cycles (8.07cy/32k FLOP vs 4.85/16k) and
// half the MFMA/ds_read/global-load instruction count per phase. Per-wave
// tile stays 64x64 = 2x2 of 32x32. A ring-4 over ksteps (32 VGPR, less than
// v7's 48 -> no spill risk; v8's extra B-ring caused scratch traffic).
// Layouts: A/B pos=lane&31, k=(lane>>5)*8+j ; D col=lane&31,
// row=(reg&3)+8*(reg>>2)+4*(lane>>5)  (m74/m101-verified).
__global__ __launch_bounds__(256, 3) void conv_v9(
        const unsigned short* __restrict__ wt2,
        const unsigned short* __restrict__ xt,
        const float* __restrict__ bias, const float* __restrict__ u_b,
        float* __restrict__ out)
{
    using frag   = __attribute__((ext_vector_type(8))) short;
    using f32x16 = __attribute__((ext_vector_type(16))) float;

    __shared__ unsigned short Xs[4 * 66 * 64];     // 33792 B resident x-tile

    const int tid  = threadIdx.x;
    const int lane = tid & 63;
    const int l31  = lane & 31;
    const int lhi  = lane >> 5;
    const int wv   = tid >> 6;
    const int wm2  = wv >> 1;
    const int wm   = wm2 * 64;
    const int wn   = (wv & 1) * 64;
    const int wnrow = wn >> 6;                     // 0 or 1: tile spatial row

    // ---- XCD-clustered bijective swizzle (grid = 32 x 2 x 32 = 2048, %8==0)
    const int f   = blockIdx.x + 32 * blockIdx.y + 64 * blockIdx.z;
    const int wid = (f & 7) * 256 + (f >> 3);
    const int b   = wid >> 6;
    const int m0  = ((wid >> 5) & 1) * 128;
    const int n0  = (wid & 31) * 128;
    const int mb  = m0 >> 7;
    const int ph0 = n0 >> 6;                       // first global image row

    const unsigned short* xtb = xt + (size_t)b * NSP * CIN;

    // ---- A-fragment base pointers (elems), wt2 chunk layout (see prepass):
    // addr(mi; slab,tap,ks) = gA32[mi] + slab*73728 + tap*8192 + ks*2048
    const unsigned short* gA32[2];
    {
        const unsigned short* base = wt2
            + (size_t)(b * 2 + mb) * 147456 + wm2 * 1024 + lane * 8;
        gA32[0] = base;
        gA32[1] = base + 512;
    }

    // ---- X-DMA map: wave wv stages X row rr=wv (global row ph0-1+wv).
    const int kcl = (lane & 7) ^ ((1 + (lane >> 3)) & 7);
    const int xsrc_lane = (lane >> 3) * CIN + kcl * 8;   // u16 offset in xt row
    const int hhx = ph0 - 1 + wv;
    const bool vrow = ((unsigned)hhx < 64u);
    unsigned short* const xdst = &Xs[(wv * 66 + 1) * 64];

    // ---- B frag-read constants. Xs[rr][cc][phys p] holds logical ch-chunk
    // (p ^ (cc&7)) (v4-verified swizzle). For (ni,dxi,ks):
    //   cc  = ni*32 + l31 + dxi,  logical k8 = ks*2 + lhi,
    //   addr = rr*4224 + cc*64 + (k8 ^ (cc&7))*8
    int bcol[2][3];
    int sw[3];
    #pragma unroll
    for (int dxi = 0; dxi < 3; ++dxi) {
        sw[dxi] = (l31 + dxi) & 7;
        #pragma unroll
        for (int ni = 0; ni < 2; ++ni)
            bcol[ni][dxi] = (ni * 32 + l31 + dxi) * 64;
    }

    f32x16 acc2[2][2];
    #pragma unroll
    for (int mi = 0; mi < 2; ++mi)
        #pragma unroll
        for (int ni = 0; ni < 2; ++ni)
            #pragma unroll
            for (int r = 0; r < 16; ++r)
                acc2[mi][ni][r] = 0.f;

    // ---- zero the column-halo cells of Xs once (cc=0 and cc=65, all 4 rows)
    {
        const int cell = tid >> 5;                 // 0..7
        const int rr   = cell >> 1;
        const int cc   = (cell & 1) ? 65 : 0;
        *reinterpret_cast<unsigned int*>(
            &Xs[(rr * 66 + cc) * 64 + (tid & 31) * 2]) = 0u;
    }

    auto stage_x = [&](int i0) {
        const unsigned short* sx = vrow
            ? xtb + (size_t)hhx * HW * CIN + i0 + xsrc_lane
            : g_zeros;
        #pragma unroll
        for (int g = 0; g < 8; ++g)
            gl_lds16(vrow ? (sx + g * 8 * CIN) : sx, xdst + g * 512);
    };

    #pragma unroll
    for (int s2 = 0; s2 < 2; ++s2) {
        const int sofs = s2 * 73728;               // slab offset (elems)

        if (s2) __syncthreads();                   // slab0 Xs reads complete

        // A ring prologue: ksteps 0,1,2 (latency hides under stage_x+barrier)
        frag afr[4][2];
        #pragma unroll
        for (int k0 = 0; k0 < 3; ++k0) {
            const int off = sofs + (k0 >> 2) * 8192 + (k0 & 3) * 2048;
            #pragma unroll
            for (int mi = 0; mi < 2; ++mi)
                afr[k0][mi] = *reinterpret_cast<const frag*>(gA32[mi] + off);
        }

        stage_x(s2 * 64);
        __syncthreads();                           // drains DMA: Xs (+A ring) ready

        #pragma unroll
        for (int kl = 0; kl < 36; ++kl) {          // kl = tap*4 + ks
            // depth-3 A prefetch (global, coalesced 1 KiB/instr)
            if (kl + 3 < 36) {
                const int nk  = kl + 3;
                const int off = sofs + (nk >> 2) * 8192 + (nk & 3) * 2048;
                #pragma unroll
                for (int mi = 0; mi < 2; ++mi)
                    afr[nk & 3][mi] =
                        *reinterpret_cast<const frag*>(gA32[mi] + off);
            }
            const int tap = kl >> 2;
            const int ks  = kl & 3;
            const int dy  = tap / 3 - 1;
            const int dx  = tap - 3 * (tap / 3) - 1;
            const int dxi = dx + 1;
            const int cb  = (wnrow + dy + 1) * 4224;   // 66*64 = 4224
            const int k8  = ks * 2 + lhi;

            frag bfr[2];
            #pragma unroll
            for (int ni = 0; ni < 2; ++ni)
                bfr[ni] = *reinterpret_cast<const frag*>(
                    &Xs[cb + bcol[ni][dxi] + ((k8 ^ sw[dxi]) << 3)]);

            __builtin_amdgcn_s_setprio(1);
            #pragma unroll
            for (int mi = 0; mi < 2; ++mi)
                #pragma unroll
                for (int ni = 0; ni < 2; ++ni)
                    acc2[mi][ni] = __builtin_amdgcn_mfma_f32_32x32x16_bf16(
                        afr[kl & 3][mi], bfr[ni], acc2[mi][ni], 0, 0, 0);
            __builtin_amdgcn_s_setprio(0);
        }
    }

    // ---- epilogue: D col=l31, row=(r&3)+8*(r>>2)+4*lhi ; dropped-out bias
    float* ob = out + (size_t)b * COUT * NSP;
    #pragma unroll
    for (int mi = 0; mi < 2; ++mi) {
        #pragma unroll
        for (int r = 0; r < 16; ++r) {
            const int row = (r & 3) + 8 * (r >> 2) + 4 * lhi;
            const int o   = m0 + wm + mi * 32 + row;
            const float bvv = (u_b[b * COUT + o] > PDROP) ? bias[o] : 0.f;
            float* orow = ob + (size_t)o * NSP + n0 + wn + l31;
            #pragma unroll
            for (int ni = 0; ni < 2; ++ni)
                orow[ni * 32] = acc2[mi][ni][r] + bvv;
        }
    }
}

// ---------------------------------------------------------------------------
// Fallback (round-1 kernel, no workspace): used only if workspace too small.
__global__ __launch_bounds__(256) void conv_fb(
        const float* __restrict__ x, const float* __restrict__ weight,
        const float* __restrict__ bias, const float* __restrict__ u_w,
        const float* __restrict__ u_b, float* __restrict__ out)
{
    using frag  = __attribute__((ext_vector_type(8))) short;
    using f32x4 = __attribute__((ext_vector_type(4))) float;

    __shared__ unsigned short As[128 * LDT];
    __shared__ unsigned short Bs[128 * LDT];

    const int tid  = threadIdx.x;
    const int lane = tid & 63;
    const int q    = lane >> 4;
    const int l15  = lane & 15;
    const int wv   = tid >> 6;
    const int wm   = (wv >> 1) * 64;
    const int wn   = (wv & 1) * 64;

    const int b  = blockIdx.z;
    const int m0 = blockIdx.y * 128;
    const int n0 = blockIdx.x * 128;

    const int arow = tid >> 1;
    const int acol = (tid & 1) * 16;
    const int pn = tid & 127;
    const int kh = (tid >> 7) * 16;
    const int p  = n0 + pn;
    const int ph = p >> 6;
    const int pw = p & 63;

    const float* xb = x + (size_t)b * CIN * NSP;

    f32x4 acc[4][4];
    #pragma unroll
    for (int i = 0; i < 4; ++i)
        #pragma unroll
        for (int j = 0; j < 4; ++j)
            acc[i][j] = (f32x4){0.f, 0.f, 0.f, 0.f};

    const int a_rd = (wm + l15) * LDT + q * 8;
    const int b_rd = (wn + l15) * LDT + q * 8;

    for (int s = 0; s < 36; ++s) {
        const int r  = s >> 2;
        const int i0 = (s & 3) * 32;

        float aw[16], au[16];
        {
            const float* wsrc = weight + (size_t)(m0 + arow) * KTOT;
            const float* usrc = u_w + (size_t)(b * COUT + m0 + arow) * KTOT;
            #pragma unroll
            for (int ii = 0; ii < 16; ++ii) {
                const int kk = (i0 + acol + ii) * 9 + r;
                aw[ii] = wsrc[kk];
                au[ii] = usrc[kk];
            }
        }

        const int hh = ph + (r / 3) - 1;
        const int ww = pw + (r % 3) - 1;
        float bx[16];
        #pragma unroll
        for (int j = 0; j < 16; ++j) bx[j] = 0.f;
        if (((unsigned)hh < 64u) && ((unsigned)ww < 64u)) {
            const float* xsrc = xb + (size_t)(i0 + kh) * NSP + hh * HW + ww;
            #pragma unroll
            for (int j = 0; j < 16; ++j) bx[j] = xsrc[(size_t)j * NSP];
        }

        __syncthreads();

        {
            union { unsigned short u16[16]; uint4 v[2]; } tu;
            #pragma unroll
            for (int ii = 0; ii < 16; ++ii)
                tu.u16[ii] = f2bf((au[ii] > PDROP) ? aw[ii] : 0.f);
            uint4* d = reinterpret_cast<uint4*>(&As[arow * LDT + acol]);
            d[0] = tu.v[0]; d[1] = tu.v[1];
        }
        {
            union { unsigned short u16[16]; uint4 v[2]; } tu;
            #pragma unroll
            for (int j = 0; j < 16; ++j) tu.u16[j] = f2bf(bx[j]);
            uint4* d = reinterpret_cast<uint4*>(&Bs[pn * LDT + kh]);
            d[0] = tu.v[0]; d[1] = tu.v[1];
        }

        __syncthreads();

        frag af[4], bfr[4];
        #pragma unroll
        for (int mi = 0; mi < 4; ++mi)
            af[mi] = *reinterpret_cast<const frag*>(&As[a_rd + mi * 16 * LDT]);
        #pragma unroll
        for (int ni = 0; ni < 4; ++ni)
            bfr[ni] = *reinterpret_cast<const frag*>(&Bs[b_rd + ni * 16 * LDT]);
        #pragma unroll
        for (int mi = 0; mi < 4; ++mi)
            #pragma unroll
            for (int ni = 0; ni < 4; ++ni)
                acc[mi][ni] = __builtin_amdgcn_mfma_f32_16x16x32_bf16(
                    af[mi], bfr[ni], acc[mi][ni], 0, 0, 0);
    }

    float* ob = out + (size_t)b * COUT * NSP;
    #pragma unroll
    for (int mi = 0; mi < 4; ++mi) {
        #pragma unroll
        for (int rg = 0; rg < 4; ++rg) {
            const int o = m0 + wm + mi * 16 + q * 4 + rg;
            const float bvv = (u_b[b * COUT + o] > PDROP) ? bias[o] : 0.f;
            float* orow = ob + (size_t)o * NSP + n0 + wn + l15;
            #pragma unroll
            for (int ni = 0; ni < 4; ++ni)
                orow[ni * 16] = acc[mi][ni][rg] + bvv;
        }
    }
}

extern "C" void kernel_launch(void* const* d_in, const int* in_sizes, int n_in,
                              void* d_out, int out_size, void* d_ws, size_t ws_size,
                              hipStream_t stream)
{
    const float* x      = (const float*)d_in[0];
    const float* weight = (const float*)d_in[1];
    const float* bias   = (const float*)d_in[2];
    const float* u_w    = (const float*)d_in[3];
    const float* u_b    = (const float*)d_in[4];
    float* out = (float*)d_out;

    const size_t wt_bytes = (size_t)BATCH * COUT * KTOT * sizeof(unsigned short); // 18.87 MB
    const size_t xt_bytes = (size_t)BATCH * NSP * CIN * sizeof(unsigned short);   // 33.55 MB
    dim3 grid(NSP / 128, COUT / 128, BATCH);   // 32 x 2 x 32 = 2048 blocks

    if (ws_size >= wt_bytes + xt_bytes) {
        unsigned short* wtp = (unsigned short*)d_ws;
        unsigned short* xtp = (unsigned short*)((char*)d_ws + wt_bytes);
        prepass<<<512 + 2048, 256, 0, stream>>>(weight, u_w, x, wtp, xtp);
        conv_v9<<<grid, 256, 0, stream>>>(wtp, xtp, bias, u_b, out);
    } else {
        conv_fb<<<grid, 256, 0, stream>>>(x, weight, bias, u_w, u_b, out);
    }
}